// Round 17
// baseline (168.976 us; speedup 1.0000x reference)
//
#include <hip/hip_runtime.h>
#include <hip/hip_fp16.h>

#define NN   40000
#define EE   640000
#define DIN  127
#define HH   128
#define NSEGS 512
#define SEGSZ 64
#define CAP  64          // ELL row capacity (Poisson deg: mean 16, P(>64) ~ 0)
#define NBUK 80          // dst-buckets of 512 nodes (d>>9); 79 used
#define NSUB 4           // phase-B sub-blocks per bucket (128-node quarters)
#define NB_PA 625        // phase-A partition blocks (1024 edges each; EE = 625*1024)
#define NB_H0 10000      // h0-build blocks
#define NB_BF 128        // set_bf blocks
#define NB_WC 192        // wcvt blocks (3*128*128/256)

typedef unsigned int uint;
typedef unsigned short ushort;
typedef _Float16 f16;
typedef __attribute__((ext_vector_type(8))) _Float16 f16x8;
typedef __attribute__((ext_vector_type(4))) float f32x4;

__device__ __forceinline__ float h2f_lo(uint v) {
    __half_raw r; r.x = (ushort)(v & 0xffff); return __half2float(__half(r));
}
__device__ __forceinline__ float h2f_hi(uint v) {
    __half_raw r; r.x = (ushort)(v >> 16); return __half2float(__half(r));
}
__device__ __forceinline__ ushort f2h(float f) {
    return __half_as_ushort(__float2half(f));
}

// ---------------- phase A: block-strided radix partition (NO global atomics) || h0 ----
// Partition block b: LDS-sort 1024 edges by bucket -> ONE coalesced 8KB run at
// regionB[b*1024], plus contiguous per-block tables bcnt[b][80], boff[b][80].
__global__ __launch_bounds__(256) void part_h0(const int* __restrict__ ei,
                                               const float* __restrict__ ew,
                                               uint2* __restrict__ regionB,
                                               int* __restrict__ bcnt,
                                               int* __restrict__ boff,
                                               const float* __restrict__ x,
                                               uint* __restrict__ h) {
    __shared__ int hist[NBUK];
    __shared__ int lbase[NBUK];
    __shared__ uint2 ord[1024];
    int b = blockIdx.x;
    int t = threadIdx.x;
    if (b < NB_PA) {
        for (int i = t; i < NBUK; i += 256) hist[i] = 0;
        __syncthreads();
        int e0 = (b * 256 + t) * 4;
        int4 ss = *(const int4*)(ei + e0);
        int4 dd = *(const int4*)(ei + EE + e0);
        float4 ww = *(const float4*)(ew + e0);
        int d[4] = {dd.x, dd.y, dd.z, dd.w};
        int s[4] = {ss.x, ss.y, ss.z, ss.w};
        float w[4] = {ww.x, ww.y, ww.z, ww.w};
        int bk[4], loc[4];
#pragma unroll
        for (int i = 0; i < 4; i++) {
            bk[i] = d[i] >> 9;
            loc[i] = atomicAdd(&hist[bk[i]], 1);
        }
        __syncthreads();
        if (t == 0) {
            int run = 0;
            for (int i = 0; i < NBUK; i++) { lbase[i] = run; run += hist[i]; }
        }
        __syncthreads();
#pragma unroll
        for (int i = 0; i < 4; i++) {
            int pos = lbase[bk[i]] + loc[i];
            ord[pos] = make_uint2((uint)s[i] | ((uint)f2h(w[i]) << 16), (uint)d[i]);
        }
        __syncthreads();
        uint2* dst = regionB + (size_t)b * 1024;
        for (int idx = t; idx < 1024; idx += 256) dst[idx] = ord[idx];
        if (t < NBUK) {
            bcnt[b * NBUK + t] = hist[t];
            boff[b * NBUK + t] = lbase[t];
        }
    } else {
        int tt = (b - NB_PA) * 256 + t;             // [0, NN*64)
        int i = tt >> 6, q = tt & 63;
        int d0 = q << 1;                            // 0..126
        float a = x[i * DIN + d0];
        float bb = (d0 + 1 < DIN) ? x[i * DIN + d0 + 1] : 0.f;
        h[tt] = (uint)f2h(a) | ((uint)f2h(bb) << 16);
    }
}

// ---------------- phase B: bucket-quarter -> ELL slots || set_bf || wcvt ----------
// Block (bk,qq): threads parallel over the 625 per-block segments of bucket bk,
// filter to the 128-node quarter, LDS counters assign slots. ~32 items/thread.
__global__ __launch_bounds__(256) void ellb_misc(const uint2* __restrict__ regionB,
                                                 const int* __restrict__ bcnt,
                                                 const int* __restrict__ boff,
                                                 uint* __restrict__ ell,
                                                 int* __restrict__ cnt,
                                                 const int* __restrict__ batches,
                                                 ushort* __restrict__ h,
                                                 const float* __restrict__ w0,
                                                 const float* __restrict__ w1,
                                                 const float* __restrict__ w2,
                                                 ushort* __restrict__ wp) {
    int b = blockIdx.x;
    int t = threadIdx.x;
    if (b < NBUK * NSUB) {
        int bk = b >> 2;                            // bucket
        int qq = b & 3;                             // 128-node quarter
        __shared__ int lc[128];
        if (t < 128) lc[t] = 0;
        __syncthreads();
        for (int sb = t; sb < NB_PA; sb += 256) {
            int cn = bcnt[sb * NBUK + bk];
            int of = boff[sb * NBUK + bk];
            const uint2* seg = regionB + (size_t)sb * 1024 + of;
            for (int i = 0; i < cn; i++) {
                uint2 r = seg[i];
                int d = (int)r.y;
                if (((d >> 7) & 3) == qq) {
                    int slot = atomicAdd(&lc[d & 127], 1);
                    if (slot < CAP) ell[(size_t)d * CAP + slot] = r.x;
                }
            }
        }
        __syncthreads();
        int node = (bk << 9) + (qq << 7) + t;
        if (t < 128 && node < NN) cnt[node << 4] = lc[t];
    } else if (b < NBUK * NSUB + NB_BF) {
        int j = (b - NBUK * NSUB) * 256 + t;
        if (j < NSEGS * SEGSZ) h[(size_t)batches[j] * HH + DIN] = 0x3C00;   // fp16 1.0
    } else {
        int idx = (b - NBUK * NSUB - NB_BF) * 256 + t;   // [0, 3*HH*HH)
        int l = idx / (HH * HH);
        int r = idx - l * (HH * HH);
        int n = r >> 7, k = r & 127;
        const float* w = (l == 0) ? w0 : (l == 1) ? w1 : w2;
        wp[idx] = f2h(w[k * HH + n]);
    }
}

// ---------------- fused GIN layer: gather (16-lane group/node, uint4, 4-deep) ----------
// 2500 blocks x 4 waves; wave's 4 groups own 4 nodes concurrently; lane loads
// uint4 (16B) so one VMEM instr moves 4 rows (1KB); 4-edge unroll.
// (8-deep tried r14: regression — TLP already saturates requests.)
__global__ __launch_bounds__(256) void gin_layer(const uint* __restrict__ h,
                                                 const int* __restrict__ cnt,
                                                 const uint* __restrict__ ell,
                                                 const ushort* __restrict__ wp,
                                                 const float* __restrict__ bias,
                                                 ushort* __restrict__ hout) {
    __shared__ __align__(16) uint lds[16 * 64];   // 16 rows x 128 f16, swizzled
    int tid = threadIdx.x;
    int wave = tid >> 6, lane = tid & 63;
    int g4 = lane >> 4, l16 = lane & 15;
    int ni = wave * 4 + g4;                        // 0..15
    int node = blockIdx.x * 16 + ni;

    int n = cnt[node << 4];
    if (n > CAP) n = CAP;
    const uint* row = ell + (size_t)node * CAP;
    uint4 self = *(const uint4*)(h + (size_t)node * 64 + l16 * 4);
    float a0 = h2f_lo(self.x), a1 = h2f_hi(self.x);
    float a2 = h2f_lo(self.y), a3 = h2f_hi(self.y);
    float a4 = h2f_lo(self.z), a5 = h2f_hi(self.z);
    float a6 = h2f_lo(self.w), a7 = h2f_hi(self.w);
    float b0 = 0.f, b1 = 0.f, b2 = 0.f, b3 = 0.f;
    float b4 = 0.f, b5 = 0.f, b6 = 0.f, b7 = 0.f;
    int p = 0;
    for (; p + 4 <= n; p += 4) {
        uint4 ee = *(const uint4*)(row + p);       // broadcast within group
        uint4 v0 = *(const uint4*)(h + (size_t)(ee.x & 0xffff) * 64 + l16 * 4);
        uint4 v1 = *(const uint4*)(h + (size_t)(ee.y & 0xffff) * 64 + l16 * 4);
        uint4 v2 = *(const uint4*)(h + (size_t)(ee.z & 0xffff) * 64 + l16 * 4);
        uint4 v3 = *(const uint4*)(h + (size_t)(ee.w & 0xffff) * 64 + l16 * 4);
        float w0 = h2f_hi(ee.x), w1 = h2f_hi(ee.y);
        float w2 = h2f_hi(ee.z), w3 = h2f_hi(ee.w);
        a0 += w0 * h2f_lo(v0.x); a1 += w0 * h2f_hi(v0.x);
        a2 += w0 * h2f_lo(v0.y); a3 += w0 * h2f_hi(v0.y);
        a4 += w0 * h2f_lo(v0.z); a5 += w0 * h2f_hi(v0.z);
        a6 += w0 * h2f_lo(v0.w); a7 += w0 * h2f_hi(v0.w);
        b0 += w1 * h2f_lo(v1.x); b1 += w1 * h2f_hi(v1.x);
        b2 += w1 * h2f_lo(v1.y); b3 += w1 * h2f_hi(v1.y);
        b4 += w1 * h2f_lo(v1.z); b5 += w1 * h2f_hi(v1.z);
        b6 += w1 * h2f_lo(v1.w); b7 += w1 * h2f_hi(v1.w);
        a0 += w2 * h2f_lo(v2.x); a1 += w2 * h2f_hi(v2.x);
        a2 += w2 * h2f_lo(v2.y); a3 += w2 * h2f_hi(v2.y);
        a4 += w2 * h2f_lo(v2.z); a5 += w2 * h2f_hi(v2.z);
        a6 += w2 * h2f_lo(v2.w); a7 += w2 * h2f_hi(v2.w);
        b0 += w3 * h2f_lo(v3.x); b1 += w3 * h2f_hi(v3.x);
        b2 += w3 * h2f_lo(v3.y); b3 += w3 * h2f_hi(v3.y);
        b4 += w3 * h2f_lo(v3.z); b5 += w3 * h2f_hi(v3.z);
        b6 += w3 * h2f_lo(v3.w); b7 += w3 * h2f_hi(v3.w);
    }
    for (; p < n; ++p) {
        uint e = row[p];
        float w = h2f_hi(e);
        uint4 v = *(const uint4*)(h + (size_t)(e & 0xffff) * 64 + l16 * 4);
        a0 += w * h2f_lo(v.x); a1 += w * h2f_hi(v.x);
        a2 += w * h2f_lo(v.y); a3 += w * h2f_hi(v.y);
        a4 += w * h2f_lo(v.z); a5 += w * h2f_hi(v.z);
        a6 += w * h2f_lo(v.w); a7 += w * h2f_hi(v.w);
    }
    a0 += b0; a1 += b1; a2 += b2; a3 += b3;
    a4 += b4; a5 += b5; a6 += b6; a7 += b7;
    uint4 o;
    o.x = (uint)f2h(a0) | ((uint)f2h(a1) << 16);
    o.y = (uint)f2h(a2) | ((uint)f2h(a3) << 16);
    o.z = (uint)f2h(a4) | ((uint)f2h(a5) << 16);
    o.w = (uint)f2h(a6) | ((uint)f2h(a7) << 16);
    int wsw = (l16 * 4) ^ ((ni & 7) << 2);         // swizzled word offset in row
    *(uint4*)(&lds[ni * 64 + wsw]) = o;
    __syncthreads();

    int n16 = lane & 15, kg = lane >> 4;
    f16x8 a[4];
#pragma unroll
    for (int s = 0; s < 4; ++s) {
        int w = (s * 16 + kg * 4) ^ ((n16 & 7) << 2);
        a[s] = *(const f16x8*)(&lds[n16 * 64 + w]);
    }
    int row0 = blockIdx.x * 16;
#pragma unroll
    for (int t = 0; t < 2; ++t) {
        int ct = wave * 2 + t;
        const f16* brow = (const f16*)wp + (size_t)(ct * 16 + n16) * HH + kg * 8;
        f16x8 bb0 = *(const f16x8*)(brow + 0);
        f16x8 bb1 = *(const f16x8*)(brow + 32);
        f16x8 bb2 = *(const f16x8*)(brow + 64);
        f16x8 bb3 = *(const f16x8*)(brow + 96);
        f32x4 c = {0.f, 0.f, 0.f, 0.f};
        c = __builtin_amdgcn_mfma_f32_16x16x32_f16(a[0], bb0, c, 0, 0, 0);
        c = __builtin_amdgcn_mfma_f32_16x16x32_f16(a[1], bb1, c, 0, 0, 0);
        c = __builtin_amdgcn_mfma_f32_16x16x32_f16(a[2], bb2, c, 0, 0, 0);
        c = __builtin_amdgcn_mfma_f32_16x16x32_f16(a[3], bb3, c, 0, 0, 0);
        float bv = bias[ct * 16 + n16];
#pragma unroll
        for (int j = 0; j < 4; j++) {
            float o2 = fmaxf(c[j] + bv, 0.f);
            hout[(size_t)(row0 + kg * 4 + j) * HH + ct * 16 + n16] = f2h(o2);
        }
    }
}

// ---------------- fused multipool + readout MLP (one block of 128 per segment) --------
__device__ __forceinline__ float block_sum(float v, float* red, int c) {
    red[c] = v;
    __syncthreads();
#pragma unroll
    for (int off = 64; off > 0; off >>= 1) {
        if (c < off) red[c] += red[c + off];
        __syncthreads();
    }
    float r = red[0];
    __syncthreads();
    return r;
}

__global__ __launch_bounds__(128) void pool_readout(const ushort* __restrict__ h,
    const int* __restrict__ batches,
    const float* __restrict__ w1, const float* __restrict__ b1,
    const float* __restrict__ g1, const float* __restrict__ be1,
    const float* __restrict__ w2, const float* __restrict__ b2,
    const float* __restrict__ g2, const float* __restrict__ be2,
    const float* __restrict__ w3, const float* __restrict__ b3,
    float* __restrict__ out) {
    __shared__ float zr[384];
    __shared__ float red[128];
    __shared__ float v1[128];
    int s = blockIdx.x, c = threadIdx.x;

    // pool gather: 4-wide unrolled -> 4 independent row loads in flight
    const int* bseg = batches + s * SEGSZ;
    float sum = 0.f, mn = INFINITY, mx = -INFINITY;
    for (int j = 0; j < SEGSZ; j += 4) {
        int4 ii = *(const int4*)(bseg + j);
        __half_raw r0; r0.x = h[(size_t)ii.x * HH + c];
        __half_raw r1; r1.x = h[(size_t)ii.y * HH + c];
        __half_raw r2; r2.x = h[(size_t)ii.z * HH + c];
        __half_raw r3; r3.x = h[(size_t)ii.w * HH + c];
        float v0 = __half2float(__half(r0));
        float vv1 = __half2float(__half(r1));
        float v2 = __half2float(__half(r2));
        float v3 = __half2float(__half(r3));
        sum += (v0 + vv1) + (v2 + v3);
        mn = fminf(mn, fminf(fminf(v0, vv1), fminf(v2, v3)));
        mx = fmaxf(mx, fmaxf(fmaxf(v0, vv1), fmaxf(v2, v3)));
    }
    zr[c] = sum * (1.f / SEGSZ);
    zr[128 + c] = mn;
    zr[256 + c] = mx;
    __syncthreads();

    // MLP1: 384-deep dot, 4 independent accumulator chains
    float ac0 = b1[c], ac1 = 0.f, ac2 = 0.f, ac3 = 0.f;
    for (int k = 0; k < 384; k += 4) {
        ac0 += zr[k + 0] * w1[(k + 0) * HH + c];
        ac1 += zr[k + 1] * w1[(k + 1) * HH + c];
        ac2 += zr[k + 2] * w1[(k + 2) * HH + c];
        ac3 += zr[k + 3] * w1[(k + 3) * HH + c];
    }
    float a = fmaxf((ac0 + ac1) + (ac2 + ac3), 0.f);
    float m = block_sum(a, red, c) * (1.f / HH);
    float d = a - m;
    float var = block_sum(d * d, red, c) * (1.f / HH);
    float v = d * rsqrtf(var + 1e-5f) * g1[c] + be1[c];
    v1[c] = v;
    __syncthreads();

    // MLP2: 128-deep dot, 4 chains
    float bc0 = b2[c], bc1 = 0.f, bc2 = 0.f, bc3 = 0.f;
    for (int k = 0; k < HH; k += 4) {
        bc0 += v1[k + 0] * w2[(k + 0) * HH + c];
        bc1 += v1[k + 1] * w2[(k + 1) * HH + c];
        bc2 += v1[k + 2] * w2[(k + 2) * HH + c];
        bc3 += v1[k + 3] * w2[(k + 3) * HH + c];
    }
    float a2 = (bc0 + bc1) + (bc2 + bc3);
    float m2 = block_sum(a2, red, c) * (1.f / HH);
    float d2 = a2 - m2;
    float var2 = block_sum(d2 * d2, red, c) * (1.f / HH);
    float t2 = d2 * rsqrtf(var2 + 1e-5f) * g2[c] + be2[c];
    float z2 = fmaxf(t2, 0.f);

    float tot = block_sum(z2 * w3[c], red, c);
    if (c == 0) out[s] = tot + b3[0];
}

extern "C" void kernel_launch(void* const* d_in, const int* in_sizes, int n_in,
                              void* d_out, int out_size, void* d_ws, size_t ws_size,
                              hipStream_t stream) {
    const float* x        = (const float*)d_in[0];
    const int*   ei       = (const int*)d_in[1];
    const float* ew       = (const float*)d_in[2];
    const int*   batches  = (const int*)d_in[3];
    const float* gw[3]    = {(const float*)d_in[5], (const float*)d_in[7], (const float*)d_in[9]};
    const float* gb[3]    = {(const float*)d_in[6], (const float*)d_in[8], (const float*)d_in[10]};
    const float* r_w1 = (const float*)d_in[11]; const float* r_b1 = (const float*)d_in[12];
    const float* ln1g = (const float*)d_in[13]; const float* ln1b = (const float*)d_in[14];
    const float* r_w2 = (const float*)d_in[15]; const float* r_b2 = (const float*)d_in[16];
    const float* ln2g = (const float*)d_in[17]; const float* ln2b = (const float*)d_in[18];
    const float* r_w3 = (const float*)d_in[19]; const float* r_b3 = (const float*)d_in[20];
    float* out = (float*)d_out;

    // workspace layout
    uint*  h0      = (uint*)d_ws;                        // NN*64 uints (fp16 x2)
    uint*  h1      = h0 + (size_t)NN * 64;               // NN*64
    uint*  wpk     = h1 + (size_t)NN * 64;               // 3*HH*HH fp16 (24576 uints)
    uint*  ell     = wpk + 3 * HH * HH / 2;              // NN*CAP uints (packed src|w)
    int*   cnt     = (int*)(ell + (size_t)NN * CAP);     // NN*16 ints (line-padded)
    uint2* regionB = (uint2*)(cnt + (size_t)NN * 16);    // NB_PA*1024 uint2 (5.12 MB)
    int*   bcnt    = (int*)(regionB + (size_t)NB_PA * 1024);  // NB_PA*NBUK
    int*   boff    = bcnt + NB_PA * NBUK;                // NB_PA*NBUK

    part_h0<<<NB_PA + NB_H0, 256, 0, stream>>>(ei, ew, regionB, bcnt, boff, x, h0);
    ellb_misc<<<NBUK * NSUB + NB_BF + NB_WC, 256, 0, stream>>>(
        regionB, bcnt, boff, ell, cnt, batches, (ushort*)h0,
        gw[0], gw[1], gw[2], (ushort*)wpk);

    uint* hin = h0;
    uint* hout = h1;
    for (int l = 0; l < 3; l++) {
        gin_layer<<<NN / 16, 256, 0, stream>>>(hin, cnt, ell,
                                               (const ushort*)wpk + (size_t)l * HH * HH,
                                               gb[l], (ushort*)hout);
        uint* tmp = hin; hin = hout; hout = tmp;
    }

    pool_readout<<<NSEGS, 128, 0, stream>>>((const ushort*)hin, batches,
                                            r_w1, r_b1, ln1g, ln1b,
                                            r_w2, r_b2, ln2g, ln2b, r_w3, r_b3, out);
}

// Round 18
// 161.330 us; speedup vs baseline: 1.0474x; 1.0474x over previous
//
#include <hip/hip_runtime.h>
#include <hip/hip_fp16.h>

#define NN   40000
#define EE   640000
#define DIN  127
#define HH   128
#define NSEGS 512
#define SEGSZ 64
#define CAP  64          // ELL row capacity (Poisson deg: mean 16, P(>64) ~ 0)
#define NBUK 80          // dst-buckets of 512 nodes (d>>9); 79 used
#define NSUB 4           // phase-B sub-blocks per bucket (128-node quarters)
#define RCAP 16384       // region capacity per bucket (mean 8.1K, std ~90)
#define NB_PA 625        // phase-A partition blocks (1024 edges each)
#define NB_H0 10000      // h0-build blocks

typedef unsigned int uint;
typedef unsigned short ushort;
typedef _Float16 f16;
typedef __attribute__((ext_vector_type(8))) _Float16 f16x8;
typedef __attribute__((ext_vector_type(4))) float f32x4;

__device__ __forceinline__ float h2f_lo(uint v) {
    __half_raw r; r.x = (ushort)(v & 0xffff); return __half2float(__half(r));
}
__device__ __forceinline__ float h2f_hi(uint v) {
    __half_raw r; r.x = (ushort)(v >> 16); return __half2float(__half(r));
}
__device__ __forceinline__ ushort f2h(float f) {
    return __half_as_ushort(__float2half(f));
}

// ---------------- prep: zero bucket counters + weights->fp16 B^T ----------------
__global__ __launch_bounds__(256) void prep(int* __restrict__ gcnt,
                                            const float* __restrict__ w0,
                                            const float* __restrict__ w1,
                                            const float* __restrict__ w2,
                                            ushort* __restrict__ wp) {
    int t = blockIdx.x * 256 + threadIdx.x;
    if (t < NBUK) gcnt[t] = 0;
    if (t < 3 * HH * HH) {
        int l = t / (HH * HH);
        int r = t - l * (HH * HH);
        int n = r >> 7, k = r & 127;
        const float* w = (l == 0) ? w0 : (l == 1) ? w1 : w2;
        wp[t] = f2h(w[k * HH + n]);
    }
}

// ---------------- phase A: LDS radix partition of edges by dst>>9 || h0 build ----------
// (r17's atomic-free variant REGRESSED: per-lane segment walks destroy coalescing.
// 50K coalesced-write global atomics are the cheaper design. Keep this form.)
__global__ __launch_bounds__(256) void part_h0(const int* __restrict__ ei,
                                               const float* __restrict__ ew,
                                               int* __restrict__ gcnt,
                                               uint2* __restrict__ region,
                                               const float* __restrict__ x,
                                               uint* __restrict__ h) {
    __shared__ int hist[NBUK];
    __shared__ int lbase[NBUK];
    __shared__ int gposs[NBUK];
    __shared__ uint2 ord[1024];
    __shared__ uint adrs[1024];
    int b = blockIdx.x;
    int t = threadIdx.x;
    if (b < NB_PA) {
        for (int i = t; i < NBUK; i += 256) hist[i] = 0;
        __syncthreads();
        int e0 = (b * 256 + t) * 4;
        int4 ss = *(const int4*)(ei + e0);
        int4 dd = *(const int4*)(ei + EE + e0);
        float4 ww = *(const float4*)(ew + e0);
        int d[4] = {dd.x, dd.y, dd.z, dd.w};
        int s[4] = {ss.x, ss.y, ss.z, ss.w};
        float w[4] = {ww.x, ww.y, ww.z, ww.w};
        int bk[4], loc[4];
#pragma unroll
        for (int i = 0; i < 4; i++) {
            bk[i] = d[i] >> 9;
            loc[i] = atomicAdd(&hist[bk[i]], 1);
        }
        __syncthreads();
        if (t == 0) {
            int run = 0;
            for (int i = 0; i < NBUK; i++) { lbase[i] = run; run += hist[i]; }
        }
        if (t < NBUK && hist[t] > 0) gposs[t] = atomicAdd(&gcnt[t], hist[t]);
        __syncthreads();
#pragma unroll
        for (int i = 0; i < 4; i++) {
            int pos = lbase[bk[i]] + loc[i];
            ord[pos] = make_uint2((uint)s[i] | ((uint)f2h(w[i]) << 16), (uint)d[i]);
            int off = gposs[bk[i]] + loc[i];
            adrs[pos] = (off < RCAP) ? (uint)(bk[i] * RCAP + off) : 0xFFFFFFFFu;
        }
        __syncthreads();
        for (int idx = t; idx < 1024; idx += 256) {
            uint a = adrs[idx];
            if (a != 0xFFFFFFFFu) region[a] = ord[idx];
        }
    } else {
        int tt = (b - NB_PA) * 256 + t;             // [0, NN*64)
        int i = tt >> 6, q = tt & 63;
        int d0 = q << 1;                            // 0..126
        float a = x[i * DIN + d0];
        float bb = (d0 + 1 < DIN) ? x[i * DIN + d0 + 1] : 0.f;
        h[tt] = (uint)f2h(a) | ((uint)f2h(bb) << 16);
    }
}

// ---------------- phase B: bucket -> ELL slots, 4 sub-blocks per bucket || set_bf ------
// Each sub-block streams the full bucket region (coalesced, i+=256 striding)
// but processes only its 128-node quarter: 320 blocks on the latency-bound path.
__global__ __launch_bounds__(256) void ellb_setbf(const uint2* __restrict__ region,
                                                  const int* __restrict__ gcnt,
                                                  uint* __restrict__ ell,
                                                  int* __restrict__ cnt,
                                                  const int* __restrict__ batches,
                                                  ushort* __restrict__ h) {
    int b = blockIdx.x;
    int t = threadIdx.x;
    if (b < NBUK * NSUB) {
        int bk = b >> 2;                            // bucket
        int qq = b & 3;                             // 128-node quarter
        __shared__ int lc[128];
        if (t < 128) lc[t] = 0;
        __syncthreads();
        int n = gcnt[bk];
        if (n > RCAP) n = RCAP;
        const uint2* reg = region + (size_t)bk * RCAP;
        for (int i = t; i < n; i += 256) {
            uint2 r = reg[i];
            int d = (int)r.y;
            if (((d >> 7) & 3) == qq) {
                int slot = atomicAdd(&lc[d & 127], 1);
                if (slot < CAP) ell[(size_t)d * CAP + slot] = r.x;
            }
        }
        __syncthreads();
        int node = (bk << 9) + (qq << 7) + t;
        if (t < 128 && node < NN) cnt[node << 4] = lc[t];
    } else {
        int j = (b - NBUK * NSUB) * 256 + t;
        if (j < NSEGS * SEGSZ) h[(size_t)batches[j] * HH + DIN] = 0x3C00;   // fp16 1.0
    }
}

// ---------------- fused GIN layer: gather (16-lane group/node, uint4, 4-deep) ----------
// 2500 blocks x 4 waves; wave's 4 groups own 4 nodes concurrently; lane loads
// uint4 (16B) so one VMEM instr moves 4 rows (1KB); 4-edge unroll.
// (8-deep tried r14: regression — TLP already saturates requests.)
__global__ __launch_bounds__(256) void gin_layer(const uint* __restrict__ h,
                                                 const int* __restrict__ cnt,
                                                 const uint* __restrict__ ell,
                                                 const ushort* __restrict__ wp,
                                                 const float* __restrict__ bias,
                                                 ushort* __restrict__ hout) {
    __shared__ __align__(16) uint lds[16 * 64];   // 16 rows x 128 f16, swizzled
    int tid = threadIdx.x;
    int wave = tid >> 6, lane = tid & 63;
    int g4 = lane >> 4, l16 = lane & 15;
    int ni = wave * 4 + g4;                        // 0..15
    int node = blockIdx.x * 16 + ni;

    int n = cnt[node << 4];
    if (n > CAP) n = CAP;
    const uint* row = ell + (size_t)node * CAP;
    uint4 self = *(const uint4*)(h + (size_t)node * 64 + l16 * 4);
    float a0 = h2f_lo(self.x), a1 = h2f_hi(self.x);
    float a2 = h2f_lo(self.y), a3 = h2f_hi(self.y);
    float a4 = h2f_lo(self.z), a5 = h2f_hi(self.z);
    float a6 = h2f_lo(self.w), a7 = h2f_hi(self.w);
    float b0 = 0.f, b1 = 0.f, b2 = 0.f, b3 = 0.f;
    float b4 = 0.f, b5 = 0.f, b6 = 0.f, b7 = 0.f;
    int p = 0;
    for (; p + 4 <= n; p += 4) {
        uint4 ee = *(const uint4*)(row + p);       // broadcast within group
        uint4 v0 = *(const uint4*)(h + (size_t)(ee.x & 0xffff) * 64 + l16 * 4);
        uint4 v1 = *(const uint4*)(h + (size_t)(ee.y & 0xffff) * 64 + l16 * 4);
        uint4 v2 = *(const uint4*)(h + (size_t)(ee.z & 0xffff) * 64 + l16 * 4);
        uint4 v3 = *(const uint4*)(h + (size_t)(ee.w & 0xffff) * 64 + l16 * 4);
        float w0 = h2f_hi(ee.x), w1 = h2f_hi(ee.y);
        float w2 = h2f_hi(ee.z), w3 = h2f_hi(ee.w);
        a0 += w0 * h2f_lo(v0.x); a1 += w0 * h2f_hi(v0.x);
        a2 += w0 * h2f_lo(v0.y); a3 += w0 * h2f_hi(v0.y);
        a4 += w0 * h2f_lo(v0.z); a5 += w0 * h2f_hi(v0.z);
        a6 += w0 * h2f_lo(v0.w); a7 += w0 * h2f_hi(v0.w);
        b0 += w1 * h2f_lo(v1.x); b1 += w1 * h2f_hi(v1.x);
        b2 += w1 * h2f_lo(v1.y); b3 += w1 * h2f_hi(v1.y);
        b4 += w1 * h2f_lo(v1.z); b5 += w1 * h2f_hi(v1.z);
        b6 += w1 * h2f_lo(v1.w); b7 += w1 * h2f_hi(v1.w);
        a0 += w2 * h2f_lo(v2.x); a1 += w2 * h2f_hi(v2.x);
        a2 += w2 * h2f_lo(v2.y); a3 += w2 * h2f_hi(v2.y);
        a4 += w2 * h2f_lo(v2.z); a5 += w2 * h2f_hi(v2.z);
        a6 += w2 * h2f_lo(v2.w); a7 += w2 * h2f_hi(v2.w);
        b0 += w3 * h2f_lo(v3.x); b1 += w3 * h2f_hi(v3.x);
        b2 += w3 * h2f_lo(v3.y); b3 += w3 * h2f_hi(v3.y);
        b4 += w3 * h2f_lo(v3.z); b5 += w3 * h2f_hi(v3.z);
        b6 += w3 * h2f_lo(v3.w); b7 += w3 * h2f_hi(v3.w);
    }
    for (; p < n; ++p) {
        uint e = row[p];
        float w = h2f_hi(e);
        uint4 v = *(const uint4*)(h + (size_t)(e & 0xffff) * 64 + l16 * 4);
        a0 += w * h2f_lo(v.x); a1 += w * h2f_hi(v.x);
        a2 += w * h2f_lo(v.y); a3 += w * h2f_hi(v.y);
        a4 += w * h2f_lo(v.z); a5 += w * h2f_hi(v.z);
        a6 += w * h2f_lo(v.w); a7 += w * h2f_hi(v.w);
    }
    a0 += b0; a1 += b1; a2 += b2; a3 += b3;
    a4 += b4; a5 += b5; a6 += b6; a7 += b7;
    uint4 o;
    o.x = (uint)f2h(a0) | ((uint)f2h(a1) << 16);
    o.y = (uint)f2h(a2) | ((uint)f2h(a3) << 16);
    o.z = (uint)f2h(a4) | ((uint)f2h(a5) << 16);
    o.w = (uint)f2h(a6) | ((uint)f2h(a7) << 16);
    int wsw = (l16 * 4) ^ ((ni & 7) << 2);         // swizzled word offset in row
    *(uint4*)(&lds[ni * 64 + wsw]) = o;
    __syncthreads();

    int n16 = lane & 15, kg = lane >> 4;
    f16x8 a[4];
#pragma unroll
    for (int s = 0; s < 4; ++s) {
        int w = (s * 16 + kg * 4) ^ ((n16 & 7) << 2);
        a[s] = *(const f16x8*)(&lds[n16 * 64 + w]);
    }
    int row0 = blockIdx.x * 16;
#pragma unroll
    for (int t = 0; t < 2; ++t) {
        int ct = wave * 2 + t;
        const f16* brow = (const f16*)wp + (size_t)(ct * 16 + n16) * HH + kg * 8;
        f16x8 bb0 = *(const f16x8*)(brow + 0);
        f16x8 bb1 = *(const f16x8*)(brow + 32);
        f16x8 bb2 = *(const f16x8*)(brow + 64);
        f16x8 bb3 = *(const f16x8*)(brow + 96);
        f32x4 c = {0.f, 0.f, 0.f, 0.f};
        c = __builtin_amdgcn_mfma_f32_16x16x32_f16(a[0], bb0, c, 0, 0, 0);
        c = __builtin_amdgcn_mfma_f32_16x16x32_f16(a[1], bb1, c, 0, 0, 0);
        c = __builtin_amdgcn_mfma_f32_16x16x32_f16(a[2], bb2, c, 0, 0, 0);
        c = __builtin_amdgcn_mfma_f32_16x16x32_f16(a[3], bb3, c, 0, 0, 0);
        float bv = bias[ct * 16 + n16];
#pragma unroll
        for (int j = 0; j < 4; j++) {
            float o2 = fmaxf(c[j] + bv, 0.f);
            hout[(size_t)(row0 + kg * 4 + j) * HH + ct * 16 + n16] = f2h(o2);
        }
    }
}

// ---------------- fused multipool + readout MLP (one block of 128 per segment) --------
__device__ __forceinline__ float block_sum(float v, float* red, int c) {
    red[c] = v;
    __syncthreads();
#pragma unroll
    for (int off = 64; off > 0; off >>= 1) {
        if (c < off) red[c] += red[c + off];
        __syncthreads();
    }
    float r = red[0];
    __syncthreads();
    return r;
}

__global__ __launch_bounds__(128) void pool_readout(const ushort* __restrict__ h,
    const int* __restrict__ batches,
    const float* __restrict__ w1, const float* __restrict__ b1,
    const float* __restrict__ g1, const float* __restrict__ be1,
    const float* __restrict__ w2, const float* __restrict__ b2,
    const float* __restrict__ g2, const float* __restrict__ be2,
    const float* __restrict__ w3, const float* __restrict__ b3,
    float* __restrict__ out) {
    __shared__ float zr[384];
    __shared__ float red[128];
    __shared__ float v1[128];
    int s = blockIdx.x, c = threadIdx.x;

    // pool gather: 4-wide unrolled -> 4 independent row loads in flight
    const int* bseg = batches + s * SEGSZ;
    float sum = 0.f, mn = INFINITY, mx = -INFINITY;
    for (int j = 0; j < SEGSZ; j += 4) {
        int4 ii = *(const int4*)(bseg + j);
        __half_raw r0; r0.x = h[(size_t)ii.x * HH + c];
        __half_raw r1; r1.x = h[(size_t)ii.y * HH + c];
        __half_raw r2; r2.x = h[(size_t)ii.z * HH + c];
        __half_raw r3; r3.x = h[(size_t)ii.w * HH + c];
        float v0 = __half2float(__half(r0));
        float vv1 = __half2float(__half(r1));
        float v2 = __half2float(__half(r2));
        float v3 = __half2float(__half(r3));
        sum += (v0 + vv1) + (v2 + v3);
        mn = fminf(mn, fminf(fminf(v0, vv1), fminf(v2, v3)));
        mx = fmaxf(mx, fmaxf(fmaxf(v0, vv1), fmaxf(v2, v3)));
    }
    zr[c] = sum * (1.f / SEGSZ);
    zr[128 + c] = mn;
    zr[256 + c] = mx;
    __syncthreads();

    // MLP1: 384-deep dot, 4 independent accumulator chains
    float ac0 = b1[c], ac1 = 0.f, ac2 = 0.f, ac3 = 0.f;
    for (int k = 0; k < 384; k += 4) {
        ac0 += zr[k + 0] * w1[(k + 0) * HH + c];
        ac1 += zr[k + 1] * w1[(k + 1) * HH + c];
        ac2 += zr[k + 2] * w1[(k + 2) * HH + c];
        ac3 += zr[k + 3] * w1[(k + 3) * HH + c];
    }
    float a = fmaxf((ac0 + ac1) + (ac2 + ac3), 0.f);
    float m = block_sum(a, red, c) * (1.f / HH);
    float d = a - m;
    float var = block_sum(d * d, red, c) * (1.f / HH);
    float v = d * rsqrtf(var + 1e-5f) * g1[c] + be1[c];
    v1[c] = v;
    __syncthreads();

    // MLP2: 128-deep dot, 4 chains
    float bc0 = b2[c], bc1 = 0.f, bc2 = 0.f, bc3 = 0.f;
    for (int k = 0; k < HH; k += 4) {
        bc0 += v1[k + 0] * w2[(k + 0) * HH + c];
        bc1 += v1[k + 1] * w2[(k + 1) * HH + c];
        bc2 += v1[k + 2] * w2[(k + 2) * HH + c];
        bc3 += v1[k + 3] * w2[(k + 3) * HH + c];
    }
    float a2 = (bc0 + bc1) + (bc2 + bc3);
    float m2 = block_sum(a2, red, c) * (1.f / HH);
    float d2 = a2 - m2;
    float var2 = block_sum(d2 * d2, red, c) * (1.f / HH);
    float t2 = d2 * rsqrtf(var2 + 1e-5f) * g2[c] + be2[c];
    float z2 = fmaxf(t2, 0.f);

    float tot = block_sum(z2 * w3[c], red, c);
    if (c == 0) out[s] = tot + b3[0];
}

extern "C" void kernel_launch(void* const* d_in, const int* in_sizes, int n_in,
                              void* d_out, int out_size, void* d_ws, size_t ws_size,
                              hipStream_t stream) {
    const float* x        = (const float*)d_in[0];
    const int*   ei       = (const int*)d_in[1];
    const float* ew       = (const float*)d_in[2];
    const int*   batches  = (const int*)d_in[3];
    const float* gw[3]    = {(const float*)d_in[5], (const float*)d_in[7], (const float*)d_in[9]};
    const float* gb[3]    = {(const float*)d_in[6], (const float*)d_in[8], (const float*)d_in[10]};
    const float* r_w1 = (const float*)d_in[11]; const float* r_b1 = (const float*)d_in[12];
    const float* ln1g = (const float*)d_in[13]; const float* ln1b = (const float*)d_in[14];
    const float* r_w2 = (const float*)d_in[15]; const float* r_b2 = (const float*)d_in[16];
    const float* ln2g = (const float*)d_in[17]; const float* ln2b = (const float*)d_in[18];
    const float* r_w3 = (const float*)d_in[19]; const float* r_b3 = (const float*)d_in[20];
    float* out = (float*)d_out;

    // workspace layout
    uint*  h0     = (uint*)d_ws;                        // NN*64 uints (fp16 x2)
    uint*  h1     = h0 + (size_t)NN * 64;               // NN*64
    uint*  wpk    = h1 + (size_t)NN * 64;               // 3*HH*HH fp16 (24576 uints)
    uint*  ell    = wpk + 3 * HH * HH / 2;              // NN*CAP uints (packed src|w)
    int*   cnt    = (int*)(ell + (size_t)NN * CAP);     // NN*16 ints (line-padded)
    uint2* region = (uint2*)(cnt + (size_t)NN * 16);    // NBUK*RCAP uint2
    int*   gcnt   = (int*)(region + (size_t)NBUK * RCAP); // NBUK

    prep<<<192, 256, 0, stream>>>(gcnt, gw[0], gw[1], gw[2], (ushort*)wpk);
    part_h0<<<NB_PA + NB_H0, 256, 0, stream>>>(ei, ew, gcnt, region, x, h0);
    ellb_setbf<<<NBUK * NSUB + 128, 256, 0, stream>>>(region, gcnt, ell, cnt, batches, (ushort*)h0);

    uint* hin = h0;
    uint* hout = h1;
    for (int l = 0; l < 3; l++) {
        gin_layer<<<NN / 16, 256, 0, stream>>>(hin, cnt, ell,
                                               (const ushort*)wpk + (size_t)l * HH * HH,
                                               gb[l], (ushort*)hout);
        uint* tmp = hin; hin = hout; hout = tmp;
    }

    pool_readout<<<NSEGS, 128, 0, stream>>>((const ushort*)hin, batches,
                                            r_w1, r_b1, ln1g, ln1b,
                                            r_w2, r_b2, ln2g, ln2b, r_w3, r_b3, out);
}